// Round 7
// baseline (330.272 us; speedup 1.0000x reference)
//
#include <hip/hip_runtime.h>
#include <math.h>

#define BB 512
#define TT 1024
#define NS 50

typedef _Float16 half2_t __attribute__((ext_vector_type(2)));

static __device__ __forceinline__ half2_t pk_h2(float a, float b) {
    auto r = __builtin_amdgcn_cvt_pkrtz(a, b);   // __fp16x2 -> bit-cast for fdot2
    return __builtin_bit_cast(half2_t, r);
}
static __device__ __forceinline__ float wave_sum_f(float v) {
    #pragma unroll
    for (int k = 32; k >= 1; k >>= 1) v += __shfl_xor(v, k, 64);
    return v;
}
static __device__ __forceinline__ int wave_sum_i(int v) {
    #pragma unroll
    for (int k = 32; k >= 1; k >>= 1) v += __shfl_xor(v, k, 64);
    return v;
}
static __device__ __forceinline__ half2_t bcast_h2(half2_t v, int lane) {
    int u = __builtin_amdgcn_readlane(__builtin_bit_cast(int, v), lane);
    return __builtin_bit_cast(half2_t, u);
}
#define FDOT(a, b, c) __builtin_amdgcn_fdot2((a), (b), (c), false)

// One prob-domain step. u: f32 state/lane. rr: rescale multiplier bits (uniform).
// kp: pending exponent. KK: applied exponent sum. EP: e-reg prefix. fraw: feat row val.
#define STEP(u, rr, kp, KK, EP, fraw) do {                                   \
    KK += kp;                                                                \
    float p_ = (u) * __int_as_float(rr);                                     \
    int pn_ = __builtin_amdgcn_update_dpp(__float_as_int(p_),                \
                __float_as_int(p_), 0xB1, 0xF, 0xF, true);                   \
    half2_t pp_ = pk_h2(p_, __int_as_float(pn_));                            \
    half2_t b0_ = bcast_h2(pp_, 0),  b1_ = bcast_h2(pp_, 2);                 \
    half2_t b2_ = bcast_h2(pp_, 4),  b3_ = bcast_h2(pp_, 6);                 \
    half2_t b4_ = bcast_h2(pp_, 8),  b5_ = bcast_h2(pp_, 10);                \
    half2_t b6_ = bcast_h2(pp_, 12), b7_ = bcast_h2(pp_, 14);                \
    half2_t b8_ = bcast_h2(pp_, 16), b9_ = bcast_h2(pp_, 18);                \
    half2_t b10_ = bcast_h2(pp_, 20), b11_ = bcast_h2(pp_, 22);              \
    half2_t b12_ = bcast_h2(pp_, 24), b13_ = bcast_h2(pp_, 26);              \
    half2_t b14_ = bcast_h2(pp_, 28), b15_ = bcast_h2(pp_, 30);              \
    half2_t b16_ = bcast_h2(pp_, 32), b17_ = bcast_h2(pp_, 34);              \
    half2_t b18_ = bcast_h2(pp_, 36), b19_ = bcast_h2(pp_, 38);              \
    half2_t b20_ = bcast_h2(pp_, 40), b21_ = bcast_h2(pp_, 42);              \
    half2_t b22_ = bcast_h2(pp_, 44), b23_ = bcast_h2(pp_, 46);              \
    half2_t b24_ = bcast_h2(pp_, 48);                                        \
    float s0_ = 0.f, s1_ = 0.f, s2_ = 0.f, s3_ = 0.f;                        \
    float s4_ = 0.f, s5_ = 0.f, s6_ = 0.f, s7_ = 0.f;                        \
    s0_ = FDOT(b0_,  EP##0,  s0_); s1_ = FDOT(b1_,  EP##1,  s1_);            \
    s2_ = FDOT(b2_,  EP##2,  s2_); s3_ = FDOT(b3_,  EP##3,  s3_);            \
    s4_ = FDOT(b4_,  EP##4,  s4_); s5_ = FDOT(b5_,  EP##5,  s5_);            \
    s6_ = FDOT(b6_,  EP##6,  s6_); s7_ = FDOT(b7_,  EP##7,  s7_);            \
    s0_ = FDOT(b8_,  EP##8,  s0_); s1_ = FDOT(b9_,  EP##9,  s1_);            \
    s2_ = FDOT(b10_, EP##10, s2_); s3_ = FDOT(b11_, EP##11, s3_);            \
    s4_ = FDOT(b12_, EP##12, s4_); s5_ = FDOT(b13_, EP##13, s5_);            \
    s6_ = FDOT(b14_, EP##14, s6_); s7_ = FDOT(b15_, EP##15, s7_);            \
    s0_ = FDOT(b16_, EP##16, s0_); s1_ = FDOT(b17_, EP##17, s1_);            \
    s2_ = FDOT(b18_, EP##18, s2_); s3_ = FDOT(b19_, EP##19, s3_);            \
    s4_ = FDOT(b20_, EP##20, s4_); s5_ = FDOT(b21_, EP##21, s5_);            \
    s6_ = FDOT(b22_, EP##22, s6_); s7_ = FDOT(b23_, EP##23, s7_);            \
    s0_ = FDOT(b24_, EP##24, s0_);                                           \
    float S_ = ((s0_ + s1_) + (s2_ + s3_)) + ((s4_ + s5_) + (s6_ + s7_));    \
    (u) = S_ * __expf(fraw);                                                 \
    int bb_ = __builtin_amdgcn_readlane(__float_as_int(u), 7);               \
    kp = ((bb_ >> 23) & 255) - 127;                                          \
    rr = (127 - kp) << 23;                                                   \
} while (0)

__global__ __launch_bounds__(64, 1) void crf_nll_kernel(
    const float* __restrict__ feat,    // (B, T, N)
    const float* __restrict__ trans,   // (N, N)
    const int*   __restrict__ tags,    // (B, T)
    const int*   __restrict__ mask,    // (B, T)
    float* __restrict__ out)           // (B,)
{
    const int b    = blockIdx.x;
    const int lane = threadIdx.x;      // lane == state j
    const int jj   = (lane < NS) ? lane : 0;

    // --- E fragments, both orientations, named regs (reg-resident).
    // fwd: ef_m = (E[2m][j], E[2m+1][j])   (contract over source i)
    // bwd: eb_m = (E[j][2m], E[j][2m+1])   (contract over dest j')
    // exp(-10000) == 0 exactly -> forbidden transitions vanish.
#define INIT_EF(m) half2_t ef##m; { \
        float x0 = __expf(trans[(2*(m) + 0) * NS + jj]); \
        float x1 = __expf(trans[(2*(m) + 1) * NS + jj]); \
        if (lane >= NS) { x0 = 0.f; x1 = 0.f; } \
        ef##m = pk_h2(x0, x1); }
#define INIT_EB(m) half2_t eb##m; { \
        float x0 = __expf(trans[jj * NS + 2*(m) + 0]); \
        float x1 = __expf(trans[jj * NS + 2*(m) + 1]); \
        if (lane >= NS) { x0 = 0.f; x1 = 0.f; } \
        eb##m = pk_h2(x0, x1); }
    INIT_EF(0)  INIT_EF(1)  INIT_EF(2)  INIT_EF(3)  INIT_EF(4)
    INIT_EF(5)  INIT_EF(6)  INIT_EF(7)  INIT_EF(8)  INIT_EF(9)
    INIT_EF(10) INIT_EF(11) INIT_EF(12) INIT_EF(13) INIT_EF(14)
    INIT_EF(15) INIT_EF(16) INIT_EF(17) INIT_EF(18) INIT_EF(19)
    INIT_EF(20) INIT_EF(21) INIT_EF(22) INIT_EF(23) INIT_EF(24)
    INIT_EB(0)  INIT_EB(1)  INIT_EB(2)  INIT_EB(3)  INIT_EB(4)
    INIT_EB(5)  INIT_EB(6)  INIT_EB(7)  INIT_EB(8)  INIT_EB(9)
    INIT_EB(10) INIT_EB(11) INIT_EB(12) INIT_EB(13) INIT_EB(14)
    INIT_EB(15) INIT_EB(16) INIT_EB(17) INIT_EB(18) INIT_EB(19)
    INIT_EB(20) INIT_EB(21) INIT_EB(22) INIT_EB(23) INIT_EB(24)
#undef INIT_EF
#undef INIT_EB

    // --- sequence length (mask is a prefix of ones); uniform across wave ---
    int cnt = 0;
    for (int t = lane; t < TT; t += 64) cnt += mask[b * TT + t];
    const int len = wave_sum_i(cnt);
    const int tm  = (len - 1) >> 1;          // cut point
    const int nf  = tm;                      // fwd steps (t = 1 .. tm)
    const int nb  = len - 1 - tm;            // bwd steps (t = len-2 .. tm); nb-nf in {0,1}

    const float* fb = feat + (size_t)b * TT * NS;

    // --- prob-domain init ---
    // fwd: u = exp(alpha0) ; bwd: u = exp(zeta_{len-1}),  zeta = beta + feat
    float uf = (lane < NS) ? __expf(trans[jj] + fb[jj]) : 0.f;
    float ub = (lane < NS) ? __expf(trans[jj * NS + 1] + fb[(size_t)(len - 1) * NS + jj]) : 0.f;
    int Kf = 0, Kb = 0, kpf, kpb, rf, rb;
    { int bb = __builtin_amdgcn_readlane(__float_as_int(uf), 7);
      kpf = ((bb >> 23) & 255) - 127; rf = (127 - kpf) << 23; }
    { int bb = __builtin_amdgcn_readlane(__float_as_int(ub), 7);
      kpb = ((bb >> 23) & 255) - 127; rb = (127 - kpb) << 23; }

    // --- depth-4 prefetch per chain; unroll 4 pairs; chains interleaved ---
    float qf0, qf1, qf2, qf3, qb0, qb1, qb2, qb3;
    {
#define LDF(q, d) { int tl = 1 + (d); tl = (tl < TT) ? tl : TT - 1; q = fb[(size_t)tl * NS + jj]; }
#define LDB(q, d) { int tl = len - 2 - (d); tl = (tl < 0) ? 0 : tl; q = fb[(size_t)tl * NS + jj]; }
        LDF(qf0, 0) LDF(qf1, 1) LDF(qf2, 2) LDF(qf3, 3)
        LDB(qb0, 0) LDB(qb1, 1) LDB(qb2, 2) LDB(qb3, 3)
#undef LDF
#undef LDB
    }

#define PSF(q, d) { float fr_ = q; int tl_ = 1 + k + 4 + (d); \
        tl_ = (tl_ < TT) ? tl_ : TT - 1; q = fb[(size_t)tl_ * NS + jj]; \
        STEP(uf, rf, kpf, Kf, ef, fr_); }
#define PSB(q, d) { float fr_ = q; int tl_ = len - 2 - (k + 4 + (d)); \
        tl_ = (tl_ < 0) ? 0 : tl_; q = fb[(size_t)tl_ * NS + jj]; \
        STEP(ub, rb, kpb, Kb, eb, fr_); }

    int k = 0;
    for (; k + 4 <= nf; k += 4) {
        PSF(qf0, 0) PSB(qb0, 0)
        PSF(qf1, 1) PSB(qb1, 1)
        PSF(qf2, 2) PSB(qb2, 2)
        PSF(qf3, 3) PSB(qb3, 3)
    }
#undef PSF
#undef PSB
    // tail (<4 pairs): rows already in prefetch regs
    if (k < nf) { STEP(uf, rf, kpf, Kf, ef, qf0); STEP(ub, rb, kpb, Kb, eb, qb0); k++; }
    if (k < nf) { STEP(uf, rf, kpf, Kf, ef, qf1); STEP(ub, rb, kpb, Kb, eb, qb1); k++; }
    if (k < nf) { STEP(uf, rf, kpf, Kf, ef, qf2); STEP(ub, rb, kpb, Kb, eb, qb2); k++; }
    if (nb > nf) {                         // one extra bwd step (row t = len-2-nf)
        float fr = fb[(size_t)(len - 2 - nf) * NS + jj];
        STEP(ub, rb, kpb, Kb, eb, fr);
    }

    // --- combine at cut: log_z = ln( sum_j uf*ub*exp(-feat[tm][j]) ) + (Kf+Kb)*ln2
    float wv = uf * ub * __expf(-fb[(size_t)tm * NS + jj]);
    if (lane >= NS) wv = 0.f;
    float W = wave_sum_f(wv);
    float log_z = __logf(W) + (float)(Kf + Kb) * 0.6931471805599453f;

    // --- gold path score (exact, log-domain), lane-parallel over t ---
    const int* tb = tags + (size_t)b * TT;
    float sc = 0.0f;
    for (int t2 = lane; t2 < len; t2 += 64) {
        int tg = tb[t2];
        sc += fb[(size_t)t2 * NS + tg];
        if (t2 >= 1) sc += trans[tb[t2 - 1] * NS + tg];
    }
    sc = wave_sum_f(sc);

    if (lane == 0) {
        sc += trans[tb[0]]                      // trans[ROOT][tag0]
            + trans[tb[len - 1] * NS + 1];      // trans[tag_last][END]
        out[b] = log_z - sc;
    }
}

extern "C" void kernel_launch(void* const* d_in, const int* in_sizes, int n_in,
                              void* d_out, int out_size, void* d_ws, size_t ws_size,
                              hipStream_t stream) {
    const float* feat  = (const float*)d_in[0];
    const float* trans = (const float*)d_in[1];
    const int*   tags  = (const int*)d_in[2];
    const int*   mask  = (const int*)d_in[3];
    float* out = (float*)d_out;
    crf_nll_kernel<<<dim3(BB), dim3(64), 0, stream>>>(feat, trans, tags, mask, out);
}

// Round 8
// 268.081 us; speedup vs baseline: 1.2320x; 1.2320x over previous
//
#include <hip/hip_runtime.h>
#include <math.h>

#define BB 512
#define TT 1024
#define NS 50

typedef _Float16 half2_t __attribute__((ext_vector_type(2)));

static __device__ __forceinline__ half2_t pk_h2(float a, float b) {
    auto r = __builtin_amdgcn_cvt_pkrtz(a, b);   // __fp16x2 -> bit-cast for fdot2
    return __builtin_bit_cast(half2_t, r);
}
static __device__ __forceinline__ float wave_sum_f(float v) {
    #pragma unroll
    for (int k = 32; k >= 1; k >>= 1) v += __shfl_xor(v, k, 64);
    return v;
}
static __device__ __forceinline__ int wave_sum_i(int v) {
    #pragma unroll
    for (int k = 32; k >= 1; k >>= 1) v += __shfl_xor(v, k, 64);
    return v;
}
#define FDOT(a, b, c) __builtin_amdgcn_fdot2((a), (b), (c), false)
#define H2(x) __builtin_bit_cast(half2_t, x)

__global__ __launch_bounds__(128, 1) void crf_nll_kernel(
    const float* __restrict__ feat,    // (B, T, N)
    const float* __restrict__ trans,   // (N, N)
    const int*   __restrict__ tags,    // (B, T)
    const int*   __restrict__ mask,    // (B, T)
    float* __restrict__ out)           // (B,)
{
    const int b    = blockIdx.x;
    const int tid  = threadIdx.x;
    const int w    = tid >> 6;        // wave 0 = forward, wave 1 = backward (zeta)
    const int lane = tid & 63;
    const int jj   = (lane < NS) ? lane : 0;

    __shared__ __align__(16) float sbuf[2][32];  // per-wave broadcast buffer (25 used)
    __shared__ float sh_comb[64];
    __shared__ float sh_sc[2];
    __shared__ int   sh_Kb;

    float* mybuf = &sbuf[w][0];

    // --- E fragments as 25 named packed-f16 regs (register-resident).
    // fwd: e_m = (E[2m][j], E[2m+1][j]);  bwd: e_m = (E[j][2m], E[j][2m+1])
    // exp(-10000) == 0 exactly -> forbidden transitions vanish.
#define INIT_E(m) half2_t e##m; { \
        int r0 = w ? (jj * NS + 2*(m)) : ((2*(m)) * NS + jj); \
        int r1 = r0 + (w ? 1 : NS); \
        float x0 = __expf(trans[r0]); \
        float x1 = __expf(trans[r1]); \
        if (lane >= NS) { x0 = 0.f; x1 = 0.f; } \
        e##m = pk_h2(x0, x1); }
    INIT_E(0)  INIT_E(1)  INIT_E(2)  INIT_E(3)  INIT_E(4)
    INIT_E(5)  INIT_E(6)  INIT_E(7)  INIT_E(8)  INIT_E(9)
    INIT_E(10) INIT_E(11) INIT_E(12) INIT_E(13) INIT_E(14)
    INIT_E(15) INIT_E(16) INIT_E(17) INIT_E(18) INIT_E(19)
    INIT_E(20) INIT_E(21) INIT_E(22) INIT_E(23) INIT_E(24)
#undef INIT_E

    // --- sequence length (mask is a prefix of ones); uniform ---
    int cnt = 0;
    for (int t = lane; t < TT; t += 64) cnt += mask[b * TT + t];
    const int len = wave_sum_i(cnt);
    const int tm  = (len - 1) >> 1;          // cut point
    const int nst = w ? (len - 1 - tm) : tm; // steps this wave runs

    const float* fb = feat + (size_t)b * TT * NS;

    // --- prob-domain init: fwd u=exp(alpha0); bwd u=exp(zeta_{len-1}), zeta=beta+feat
    float u;
    if (w == 0) u = (lane < NS) ? __expf(trans[jj] + fb[jj]) : 0.f;
    else        u = (lane < NS) ? __expf(trans[jj * NS + 1] + fb[(size_t)(len - 1) * NS + jj]) : 0.f;
    int K = 0, kp, rr;
    { int bb2 = __builtin_amdgcn_readlane(__float_as_int(u), 7);
      kp = ((bb2 >> 23) & 255) - 127; rr = (127 - kp) << 23; }

    // --- one step. eexp = exp(feat row value), precomputed off-chain. ---
    auto step = [&](float eexp) {
        K += kp;
        float p = u * __int_as_float(rr);             // lane7 in [1,2); others e^±spread
        int pn_ = __builtin_amdgcn_update_dpp(
            __float_as_int(p), __float_as_int(p), 0xB1, 0xF, 0xF, true); // lane^1
        float pnf = __int_as_float(pn_);
        bool od = (lane & 1);
        float lo = od ? pnf : p;                      // pair-symmetric pack:
        float hi = od ? p : pnf;                      // both lanes make same dword
        half2_t pk = pk_h2(lo, hi);
        mybuf[lane >> 1] = __builtin_bit_cast(float, pk);  // dup same-addr write: ok
        __asm__ volatile("s_waitcnt lgkmcnt(0)" ::: "memory");
        const float4* m4 = (const float4*)mybuf;      // broadcast reads: all lanes
        float4 c0 = m4[0], c1 = m4[1], c2 = m4[2], c3 = m4[3];  // same address
        float4 c4 = m4[4], c5 = m4[5], c6 = m4[6];
        float s0 = 0.f, s1 = 0.f, s2 = 0.f, s3 = 0.f;
        float s4 = 0.f, s5 = 0.f, s6 = 0.f, s7 = 0.f;
        s0 = FDOT(H2(c0.x), e0,  s0); s1 = FDOT(H2(c0.y), e1,  s1);
        s2 = FDOT(H2(c0.z), e2,  s2); s3 = FDOT(H2(c0.w), e3,  s3);
        s4 = FDOT(H2(c1.x), e4,  s4); s5 = FDOT(H2(c1.y), e5,  s5);
        s6 = FDOT(H2(c1.z), e6,  s6); s7 = FDOT(H2(c1.w), e7,  s7);
        s0 = FDOT(H2(c2.x), e8,  s0); s1 = FDOT(H2(c2.y), e9,  s1);
        s2 = FDOT(H2(c2.z), e10, s2); s3 = FDOT(H2(c2.w), e11, s3);
        s4 = FDOT(H2(c3.x), e12, s4); s5 = FDOT(H2(c3.y), e13, s5);
        s6 = FDOT(H2(c3.z), e14, s6); s7 = FDOT(H2(c3.w), e15, s7);
        s0 = FDOT(H2(c4.x), e16, s0); s1 = FDOT(H2(c4.y), e17, s1);
        s2 = FDOT(H2(c4.z), e18, s2); s3 = FDOT(H2(c4.w), e19, s3);
        s4 = FDOT(H2(c5.x), e20, s4); s5 = FDOT(H2(c5.y), e21, s5);
        s6 = FDOT(H2(c5.z), e22, s6); s7 = FDOT(H2(c5.w), e23, s7);
        s0 = FDOT(H2(c6.x), e24, s0);
        float S = ((s0 + s1) + (s2 + s3)) + ((s4 + s5) + (s6 + s7));
        u = S * eexp;                                  // dead lanes: e==0 -> u stays 0
        int bb2 = __builtin_amdgcn_readlane(__float_as_int(u), 7);  // lane7 never dead
        kp = ((bb2 >> 23) & 255) - 127;
        rr = (127 - kp) << 23;
    };

    // --- depth-8 prefetch, PRE-EXP'D (exp off critical chain), unrolled x8 ---
    float q0, q1, q2, q3, q4, q5, q6, q7;
    {
        int t0 = w ? (len - 2) : 1;
        int st = w ? -1 : 1;
#define LD(qr, d) { int tl = t0 + st * (d); tl = (tl < 0) ? 0 : ((tl < TT) ? tl : TT - 1); \
                    qr = __expf(fb[(size_t)tl * NS + jj]); }
        LD(q0, 0) LD(q1, 1) LD(q2, 2) LD(q3, 3) LD(q4, 4) LD(q5, 5) LD(q6, 6) LD(q7, 7)
#undef LD
    }

#define PF_STEP(qr, d) { \
        float e_ = qr; \
        int kl = k + 8 + (d); \
        int tl = w ? (len - 2 - kl) : (1 + kl); \
        tl = (tl < 0) ? 0 : ((tl < TT) ? tl : TT - 1); \
        qr = __expf(fb[(size_t)tl * NS + jj]); \
        step(e_); }

    int k = 0;
    for (; k + 8 <= nst; k += 8) {
        PF_STEP(q0, 0) PF_STEP(q1, 1) PF_STEP(q2, 2) PF_STEP(q3, 3)
        PF_STEP(q4, 4) PF_STEP(q5, 5) PF_STEP(q6, 6) PF_STEP(q7, 7)
    }
#undef PF_STEP
    for (; k < nst; ++k) {                    // tail <8 steps, rows L1-hot
        int tl = w ? (len - 2 - k) : (1 + k);
        step(__expf(fb[(size_t)tl * NS + jj]));
    }

    // --- bwd publishes ub*exp(-feat[tm]) (= exp(beta[tm]) scaled) and Kb ---
    if (w == 1) {
        sh_comb[lane] = u * __expf(-fb[(size_t)tm * NS + jj]);  // 0 for dead lanes
        if (lane == 0) sh_Kb = K;
    }

    // --- gold path score (exact, log-domain): both waves, stride-128 over t ---
    const int* tb = tags + (size_t)b * TT;
    float sc = 0.0f;
    for (int t2 = tid; t2 < len; t2 += 128) {
        int tg = tb[t2];
        sc += fb[(size_t)t2 * NS + tg];
        if (t2 >= 1) sc += trans[tb[t2 - 1] * NS + tg];
    }
    sc = wave_sum_f(sc);
    if (lane == 0) sh_sc[w] = sc;

    __syncthreads();

    if (w == 0) {
        // log_z = ln( sum_j uf_j * ub_j * exp(-feat[tm][j]) ) + (Kf+Kb)*ln2
        float wv = u * sh_comb[lane];         // dead lanes contribute 0
        float W = wave_sum_f(wv);
        float log_z = __logf(W) + (float)(K + sh_Kb) * 0.6931471805599453f;
        if (lane == 0) {
            float sct = sh_sc[0] + sh_sc[1]
                      + trans[tb[0]]                      // trans[ROOT][tag0]
                      + trans[tb[len - 1] * NS + 1];      // trans[tag_last][END]
            out[b] = log_z - sct;
        }
    }
}

extern "C" void kernel_launch(void* const* d_in, const int* in_sizes, int n_in,
                              void* d_out, int out_size, void* d_ws, size_t ws_size,
                              hipStream_t stream) {
    const float* feat  = (const float*)d_in[0];
    const float* trans = (const float*)d_in[1];
    const int*   tags  = (const int*)d_in[2];
    const int*   mask  = (const int*)d_in[3];
    float* out = (float*)d_out;
    crf_nll_kernel<<<dim3(BB), dim3(128), 0, stream>>>(feat, trans, tags, mask, out);
}